// Round 6
// baseline (482.774 us; speedup 1.0000x reference)
//

#include <hip/hip_runtime.h>

// R24b: resubmit of R24 (container infra failure, no kernel data; OOB/barrier/
// layout audit clean). Wave-independent recurrence — NO per-step barrier.
// Evidence chain: R20 (-37% MFMA) and R21 (-50% per-CU work) = 0 gain;
// R22/R23 chain cuts = all the gain -> per-step serial chain is everything.
// The remaining big term is the cross-wave barrier + LDS round-trip for h
// (256x, 1 wave/SIMD, nothing hides it). Fix: shard BATCH ROWS across waves
// (2 rows/wave), not units. Each wave computes full z(2x200) for its rows;
// h stays in-wave, redistributed via shfl (~50cy) instead of
// write->barrier->read. Uk B-frags duplicated per wave (128 VGPR; storage
// not compute). e@Wk+b hoisted per chunk to LDS as bf16 xgl (R20's exact
// treatment, absmax held at 0.00390625 there) so per-step K=64. Barriers:
// 16/chunk -> 3/chunk. Dense head + gather machinery unchanged from R23.

typedef unsigned short u16;
typedef unsigned int   u32;
typedef float f32x4 __attribute__((ext_vector_type(4)));
typedef short s16x8 __attribute__((ext_vector_type(8)));

__device__ __forceinline__ float bf2f(u16 u){
  union { u32 i; float f; } v; v.i = ((u32)u) << 16; return v.f;
}
__device__ __forceinline__ u16 f2bf(float f){
  union { float fl; u32 i; } v; v.fl = f;
  u32 r = v.i + 0x7fffu + ((v.i >> 16) & 1u);   // RNE
  return (u16)(r >> 16);
}
__device__ __forceinline__ float frcp(float x){ return __builtin_amdgcn_rcpf(x); }
__device__ __forceinline__ float sigm_f(float x){          // fast sigmoid
  float e = __expf(-x);
  return frcp(1.f + e);
}
__device__ __forceinline__ float tanh_f(float x){          // fast tanh, clamped
  x = fminf(fmaxf(x, -15.f), 15.f);
  float e = __expf(-2.f * x);
  return (1.f - e) * frcp(1.f + e);
}
__device__ __forceinline__ f32x4 mf(s16x8 a, s16x8 b, f32x4 c){
  return __builtin_amdgcn_mfma_f32_16x16x32_bf16(a, b, c, 0, 0, 0);
}
__device__ __forceinline__ float ldf(const void* p, int i, bool f32in){
  if (f32in) return ((const float*)p)[i];
  return bf2f(((const u16*)p)[i]);
}

#define TPB 256
#define RPB 8      // batch rows per block -> 256 blocks, 1 block/CU

extern "C" __global__ __launch_bounds__(TPB, 1) void LSTM_Seq2Dis_15272903704706_kernel(
    const int* idx, const void* emb, const void* Wk, const void* Uk,
    const void* bias, const void* W1, const void* b1,
    const void* W2, const void* b2, float* out)
{
  __shared__ __align__(16) u16 ebuf[8][2][512];    // e A-frags, 128 m-rows (16 KB)
  __shared__ __align__(16) u16 xgl[16*8*4*52];     // xg+b bf16 [m][gate][unit] (52 KB)
  __shared__ __align__(16) u16 hbuf[8][2][512];    // chunk h for dense head (16 KB)
  __shared__ __align__(16) u16 dwork[4][2][512];   // per-wave d1 scratch (8 KB)
  __shared__ int   tokl[2048];                     // token ids [s][r], r 0..7 (8 KB)
  __shared__ int   s_f32;

  const int tid = threadIdx.x;
  const int wv  = tid >> 6, ln = tid & 63;
  const int r0  = blockIdx.x * RPB;

  if (tid == 0){
    const u32* ew = (const u32*)emb;
    int hits = 0;
    for (int i = 0; i < 64; i++){
      u32 ef = (ew[i] >> 7) & 0xFFu;
      if (ef >= 112u && ef <= 127u) hits++;
    }
    s_f32 = (hits < 32) ? 1 : 0;
  }

  for (int i = tid; i < 8*2*512; i += TPB) ((u16*)ebuf)[i] = 0;
  for (int i = tid; i < 8*2*512; i += TPB) ((u16*)hbuf)[i] = 0;
  for (int i = tid; i < 2048;    i += TPB){
    int r = i & 7, s = i >> 3;
    tokl[i] = idx[(r0 + r)*256 + s];
  }
  __syncthreads();
  const bool f32in = (s_f32 != 0);

  const int cbase = ln & 15;

  // ---- Uk B-frags: ALL units, gate-major. Tile (g,u): col = g*50 + u*16 + c.
  // Every wave holds the full set (waves shard rows, not cols). 128 VGPR.
  s16x8 ukf[4][4][2];
  #pragma unroll
  for (int g = 0; g < 4; g++){
    #pragma unroll
    for (int u = 0; u < 4; u++){
      const int unit = u*16 + cbase;
      const int col  = g*50 + unit;
      #pragma unroll
      for (int kt = 0; kt < 2; kt++){
        s16x8 v;
        #pragma unroll
        for (int j = 0; j < 8; j++){
          int k = kt*32 + ((ln >> 4) << 3) + j;
          float w = (unit < 50 && k < 50) ? ldf(Uk, k*200 + col, f32in) : 0.f;
          v[j] = (short)f2bf(w);
        }
        ukf[g][u][kt] = v;
      }
    }
  }

  // ---- Wk B-frags for the per-chunk xg-GEMM: unit-group sharded by wave.
  const int xunit = wv*16 + cbase;
  s16x8 wkf[4][2];
  float bgx[4];
  #pragma unroll
  for (int g = 0; g < 4; g++){
    const int col = g*50 + xunit;
    bgx[g] = (xunit < 50) ? ldf(bias, col, f32in) : 0.f;
    #pragma unroll
    for (int kt = 0; kt < 2; kt++){
      s16x8 v;
      #pragma unroll
      for (int j = 0; j < 8; j++){
        int k = kt*32 + ((ln >> 4) << 3) + j;
        float w = (xunit < 50 && k < 50) ? ldf(Wk, k*200 + col, f32in) : 0.f;
        v[j] = (short)f2bf(w);
      }
      wkf[g][kt] = v;
    }
  }

  // ---- dense W1 fragments + b1/W2 (unchanged from R23) ----
  s16x8 w1f[4][2];
  float b1v[4], w2v[4];
  #pragma unroll
  for (int nt = 0; nt < 4; nt++){
    int c = nt*16 + (ln & 15);
    b1v[nt] = (c < 50) ? ldf(b1, c, f32in) : 0.f;
    w2v[nt] = (c < 50) ? ldf(W2, c, f32in) : 0.f;
    #pragma unroll
    for (int kt = 0; kt < 2; kt++){
      s16x8 v;
      #pragma unroll
      for (int j = 0; j < 8; j++){
        int k = kt*32 + ((ln >> 4) << 3) + j;
        v[j] = (short)((k < 50 && c < 50) ? f2bf(ldf(W1, k*50 + c, f32in)) : (u16)0);
      }
      w1f[nt][kt] = v;
    }
  }
  const float b2s = ldf(b2, 0, f32in);

  const int gr = tid / 50, gj = tid - gr*50;      // gather threads 0..199

  // ---- step-phase lane constants ----
  const int srcl = ln & 15;          // redistribute source lane
  const int ubit = (ln >> 4) & 1;    // which u-tile within the pass
  const int rbit = ln >> 5;          // row within the wave's 2 rows
  const int grow = wv*2 + rbit;      // block row this lane's gates handle
  const int U0   = ln & 31;          // pass0 unit (0..31, always valid)
  const int U1   = 32 + (ln & 31);   // pass1 unit (32..63)
  const bool v1  = (U1 < 50);
  const int hsub = (((U0 >> 3) << 4))*8 + (U0 & 7);   // hbuf inner idx part
  float creg0 = 0.f, creg1 = 0.f;    // cell state (unit U0 / U1, row rbit)
  s16x8 av0 = {0,0,0,0,0,0,0,0};     // h A-frag, k 0..31
  s16x8 av1 = {0,0,0,0,0,0,0,0};     // h A-frag, k 32..63

  auto dense_head = [&](int tcd){
    #pragma unroll
    for (int p = 0; p < 2; p++){
      const int mt = 2*wv + p;
      s16x8 a0 = *(const s16x8*)&hbuf[mt][0][ln*8];
      s16x8 a1 = *(const s16x8*)&hbuf[mt][1][ln*8];
      #pragma unroll
      for (int nt = 0; nt < 4; nt++){             // d1 = relu(h@W1+b1)
        f32x4 acc = {0.f,0.f,0.f,0.f};
        acc = mf(a0, w1f[nt][0], acc);
        acc = mf(a1, w1f[nt][1], acc);
        int c = nt*16 + (ln & 15);
        #pragma unroll
        for (int r = 0; r < 4; r++){
          float v = fmaxf(acc[r] + b1v[nt], 0.f);
          int row16 = ((ln >> 4) << 2) + r;
          dwork[wv][c >> 5][(row16 + (((c & 31) >> 3) << 4))*8 + (c & 7)] = f2bf(v);
        }
      }
      s16x8 d0 = *(const s16x8*)&dwork[wv][0][ln*8];
      s16x8 d1 = *(const s16x8*)&dwork[wv][1][ln*8];
      float part[4] = {0.f,0.f,0.f,0.f};
      #pragma unroll
      for (int nt = 0; nt < 4; nt++){             // d2 = relu(d1@W1+b1) . W2
        f32x4 acc = {0.f,0.f,0.f,0.f};
        acc = mf(d0, w1f[nt][0], acc);
        acc = mf(d1, w1f[nt][1], acc);
        #pragma unroll
        for (int r = 0; r < 4; r++)
          part[r] += fmaxf(acc[r] + b1v[nt], 0.f) * w2v[nt];
      }
      #pragma unroll
      for (int d = 1; d < 16; d <<= 1)
        #pragma unroll
        for (int r = 0; r < 4; r++) part[r] += __shfl_xor(part[r], d, 16);
      if ((ln & 15) == 0){
        int qq = ln >> 4;
        #pragma unroll
        for (int r = 0; r < 4; r++){
          int m = mt*16 + (qq << 2) + r;
          int sl8 = m >> 3, rb = m & 7;
          float z = part[r] + b2s;
          z = fmaxf(fminf(z, 1.0f), -1.0f);       // safety clamp
          out[(r0 + rb)*256 + tcd + sl8] = sigm_f(z);
        }
      }
    }
  };

  for (int ch = 0; ch < 16; ch++){
    const int tc = ch*16;

    // ---- gather e -> ebuf frag layout (128 m-rows = sl*8+row, K=50) ----
    if (tid < 200){
      float ev[16];
      #pragma unroll
      for (int sl = 0; sl < 16; sl++)
        ev[sl] = ldf(emb, tokl[(tc + sl)*8 + gr]*50 + gj, f32in);
      #pragma unroll
      for (int sl = 0; sl < 16; sl++){
        int m = sl*8 + gr;
        ebuf[m >> 4][gj >> 5][((m & 15) + (((gj & 31) >> 3) << 4))*8 + (gj & 7)] = f2bf(ev[sl]);
      }
      #pragma unroll
      for (int sl = 0; sl < 16; sl++)
        ev[sl] = ldf(emb, tokl[(tc + sl)*8 + gr + 4]*50 + gj, f32in);
      #pragma unroll
      for (int sl = 0; sl < 16; sl++){
        int m = sl*8 + gr + 4;
        ebuf[m >> 4][gj >> 5][((m & 15) + (((gj & 31) >> 3) << 4))*8 + (gj & 7)] = f2bf(ev[sl]);
      }
    }
    if (ch > 0) dense_head(tc - 16);    // prev chunk's head, overlaps gather
    __syncthreads();                     // ebuf ready; hbuf consumed

    // ---- xg-GEMM: xg = e(128x50) @ Wk(50x200)gate-major + b -> xgl bf16 ----
    #pragma unroll
    for (int mt = 0; mt < 8; mt++){
      s16x8 e0 = *(const s16x8*)&ebuf[mt][0][ln*8];
      s16x8 e1 = *(const s16x8*)&ebuf[mt][1][ln*8];
      #pragma unroll
      for (int g = 0; g < 4; g++){
        f32x4 acc = {0.f,0.f,0.f,0.f};
        acc = mf(e0, wkf[g][0], acc);
        acc = mf(e1, wkf[g][1], acc);
        if (xunit < 50){
          #pragma unroll
          for (int r = 0; r < 4; r++){
            int m = mt*16 + ((ln >> 4) << 2) + r;
            xgl[(m*4 + g)*52 + xunit] = f2bf(acc[r] + bgx[g]);
          }
        }
      }
    }
    __syncthreads();                     // xgl ready for all waves

    // ---- 16 recurrence steps: NO BARRIER (wave-private h) ----
    for (int sl = 0; sl < 16; sl++){
      const int xbase = (sl*8 + grow)*208;     // (m*4 + g)*52 = m*208 + g*52

      float xa[4], xb[4];
      #pragma unroll
      for (int g = 0; g < 4; g++) xa[g] = bf2f(xgl[xbase + g*52 + U0]);
      #pragma unroll
      for (int g = 0; g < 4; g++) xb[g] = v1 ? bf2f(xgl[xbase + g*52 + U1]) : 0.f;

      // pass 0: tiles u=0,1 (units 0..31)
      f32x4 pa[4], pb[4];
      #pragma unroll
      for (int g = 0; g < 4; g++){
        f32x4 a = {0.f,0.f,0.f,0.f};
        a = mf(av0, ukf[g][0][0], a);  a = mf(av1, ukf[g][0][1], a);
        pa[g] = a;
        f32x4 b = {0.f,0.f,0.f,0.f};
        b = mf(av0, ukf[g][1][0], b);  b = mf(av1, ukf[g][1][1], b);
        pb[g] = b;
      }
      float z0[4];
      #pragma unroll
      for (int g = 0; g < 4; g++){
        float b00 = __shfl(pa[g][0], srcl);
        float b01 = __shfl(pa[g][1], srcl);
        float b10 = __shfl(pb[g][0], srcl);
        float b11 = __shfl(pb[g][1], srcl);
        float t0 = ubit ? b10 : b00;
        float t1 = ubit ? b11 : b01;
        z0[g] = (rbit ? t1 : t0) + xa[g];
      }
      float iv0 = sigm_f(z0[0]), fv0 = sigm_f(z0[1]);
      float gv0 = tanh_f(z0[2]), ov0 = sigm_f(z0[3]);
      float c0 = fv0 * creg0 + iv0 * gv0;
      creg0 = c0;
      u32 hb0 = (u32)f2bf(ov0 * tanh_f(c0));

      // pass 1: tiles u=2,3 (units 32..49, rest masked)
      #pragma unroll
      for (int g = 0; g < 4; g++){
        f32x4 a = {0.f,0.f,0.f,0.f};
        a = mf(av0, ukf[g][2][0], a);  a = mf(av1, ukf[g][2][1], a);
        pa[g] = a;
        f32x4 b = {0.f,0.f,0.f,0.f};
        b = mf(av0, ukf[g][3][0], b);  b = mf(av1, ukf[g][3][1], b);
        pb[g] = b;
      }
      float z1[4];
      #pragma unroll
      for (int g = 0; g < 4; g++){
        float b00 = __shfl(pa[g][0], srcl);
        float b01 = __shfl(pa[g][1], srcl);
        float b10 = __shfl(pb[g][0], srcl);
        float b11 = __shfl(pb[g][1], srcl);
        float t0 = ubit ? b10 : b00;
        float t1 = ubit ? b11 : b01;
        z1[g] = (rbit ? t1 : t0) + xb[g];
      }
      float iv1 = sigm_f(z1[0]), fv1 = sigm_f(z1[1]);
      float gv1 = tanh_f(z1[2]), ov1 = sigm_f(z1[3]);
      float c1 = fv1 * creg1 + iv1 * gv1;
      creg1 = c1;
      u32 hb1 = v1 ? (u32)f2bf(ov1 * tanh_f(c1)) : 0u;

      // hbuf for dense head (read only after chunk-end barrier)
      {
        int m = sl*8 + grow;
        hbuf[m >> 4][0][(m & 15)*8 + hsub] = (u16)hb0;
        if (v1) hbuf[m >> 4][1][(m & 15)*8 + hsub] = (u16)hb1;
      }

      // repack next step's h A-frags intra-wave (shfl; no LDS round-trip)
      u32 w0[8], w1[8];
      #pragma unroll
      for (int j = 0; j < 8; j++){
        int k0 = ((ln >> 4) << 3) + j;               // unit for av0 / av1-32
        int s  = (srcl*32 + k0) & 63;                // src lane: row*32 + unit%32
        w0[j] = (u32)__shfl((int)hb0, s);
        w1[j] = (u32)__shfl((int)hb1, s);
      }
      union { u32 w[4]; s16x8 v; } p0, p1;
      #pragma unroll
      for (int i = 0; i < 4; i++){
        p0.w[i] = w0[2*i] | (w0[2*i+1] << 16);
        p1.w[i] = w1[2*i] | (w1[2*i+1] << 16);
      }
      av0 = p0.v;
      av1 = p1.v;
    }
    __syncthreads();                     // hbuf complete; xgl/ebuf reusable
  }

  dense_head(240);                       // last chunk's head
}

extern "C" void kernel_launch(void* const* d_in, const int* in_sizes, int n_in,
                              void* d_out, int out_size, void* d_ws, size_t ws_size,
                              hipStream_t stream) {
  (void)in_sizes; (void)n_in; (void)out_size; (void)d_ws; (void)ws_size;
  hipLaunchKernelGGL(LSTM_Seq2Dis_15272903704706_kernel,
                     dim3(256), dim3(TPB), 0, stream,
                     (const int*)d_in[0], d_in[1], d_in[2], d_in[3], d_in[4],
                     d_in[5], d_in[6], d_in[7], d_in[8], (float*)d_out);
}

// Round 7
// 305.770 us; speedup vs baseline: 1.5789x; 1.5789x over previous
//

#include <hip/hip_runtime.h>

// R25 = R23 (verified 242us, absmax 0.0039) + three OFF-CHAIN moves.
// R24b post-mortem: barrier-free wave-private recurrence = 434us (2x WORSE):
// duplicated 32 MFMA/wave/step + 3 dependent bpermute stages cost far more
// than the 1 barrier/step they removed. Reverted to R23 structure.
// R25 changes (step math bit-identical up to ah+ae f32 association):
//  1. Split-K: ae[t] = e-part MFMAs precomputed PRE-barrier from prefetched
//     e-frags; post-barrier chain = 2-dep h-MFMA + v_add (was 4-dep chain).
//  2. Reg-staged gather (T14): chunk ch+1's 32 emb loads issued at ch start,
//     latency drains under steps 0-1's barriers; ds_write at ch+1 start into
//     double-buffered ering. Gather leaves the serial timeline.
//  3. Dense head out of the step loop: head(ch-1) runs at ch start (pattern
//     validated by R24b's passing run), removing the sl==15 serial tail.

typedef unsigned short u16;
typedef unsigned int   u32;
typedef float f32x4 __attribute__((ext_vector_type(4)));
typedef short s16x8 __attribute__((ext_vector_type(8)));

__device__ __forceinline__ float bf2f(u16 u){
  union { u32 i; float f; } v; v.i = ((u32)u) << 16; return v.f;
}
__device__ __forceinline__ u16 f2bf(float f){
  union { float fl; u32 i; } v; v.fl = f;
  u32 r = v.i + 0x7fffu + ((v.i >> 16) & 1u);   // RNE
  return (u16)(r >> 16);
}
__device__ __forceinline__ float frcp(float x){ return __builtin_amdgcn_rcpf(x); }
__device__ __forceinline__ float sigm_f(float x){          // fast sigmoid
  float e = __expf(-x);
  return frcp(1.f + e);
}
__device__ __forceinline__ float tanh_f(float x){          // fast tanh, clamped
  x = fminf(fmaxf(x, -15.f), 15.f);
  float e = __expf(-2.f * x);
  return (1.f - e) * frcp(1.f + e);
}
__device__ __forceinline__ f32x4 mf(s16x8 a, s16x8 b, f32x4 c){
  return __builtin_amdgcn_mfma_f32_16x16x32_bf16(a, b, c, 0, 0, 0);
}
__device__ __forceinline__ float ldf(const void* p, int i, bool f32in){
  if (f32in) return ((const float*)p)[i];
  return bf2f(((const u16*)p)[i]);
}

#define TPB 256
#define RPB 8      // batch rows per block -> 256 blocks, 1 block/CU

extern "C" __global__ __launch_bounds__(TPB, 1) void LSTM_Seq2Dis_15272903704706_kernel(
    const int* idx, const void* emb, const void* Wk, const void* Uk,
    const void* bias, const void* W1, const void* b1,
    const void* W2, const void* b2, float* out)
{
  __shared__ __align__(16) u16 ering[2][16][1024]; // e frags, DOUBLE buffer (64 KB)
  __shared__ __align__(16) u16 abuf[2][1024];      // h frags, double buffer
  __shared__ __align__(16) u16 hbuf[8][2][512];    // chunk h for dense head (16 KB)
  __shared__ __align__(16) u16 dwork[4][2][512];   // per-wave d1 scratch
  __shared__ int   tokl[2048];                     // token ids [s][r], r 0..7
  __shared__ int   s_f32;

  const int tid = threadIdx.x;
  const int wv  = tid >> 6, ln = tid & 63;
  const int r0  = blockIdx.x * RPB;

  if (tid == 0){
    const u32* ew = (const u32*)emb;
    int hits = 0;
    for (int i = 0; i < 64; i++){
      u32 ef = (ew[i] >> 7) & 0xFFu;
      if (ef >= 112u && ef <= 127u) hits++;
    }
    s_f32 = (hits < 32) ? 1 : 0;
  }

  for (int i = tid; i < 2*16*1024; i += TPB) ((u16*)ering)[i] = 0;
  for (int i = tid; i < 2*1024;   i += TPB) ((u16*)abuf)[i]  = 0;
  for (int i = tid; i < 8*2*512;  i += TPB) ((u16*)hbuf)[i]  = 0;
  for (int i = tid; i < 2048;     i += TPB){
    int r = i & 7, s = i >> 3;
    tokl[i] = idx[(r0 + r)*256 + s];
  }
  __syncthreads();
  const bool f32in = (s_f32 != 0);

  // ---- z-GEMM B-frags, GATE-MAJOR cols (R22/R23-verified): lane owns unit
  // jown = wv*16 + (ln&15); tile t = gate t, B col = t*50 + jown.
  const int jown = wv*16 + (ln & 15);
  const bool jval = (jown < 50);
  s16x8 bz[4][4];
  #pragma unroll
  for (int t = 0; t < 4; t++){
    const int col = t*50 + jown;
    #pragma unroll
    for (int kt = 0; kt < 4; kt++){
      s16x8 v;
      #pragma unroll
      for (int j = 0; j < 8; j++){
        int k = kt*32 + ((ln >> 4) << 3) + j;
        float w = 0.f;
        if (jval){
          if (k < 50)                  w = ldf(Uk, k*200 + col, f32in);
          else if (k >= 64 && k < 114) w = ldf(Wk, (k-64)*200 + col, f32in);
        }
        v[j] = (short)f2bf(w);
      }
      bz[t][kt] = v;
    }
  }
  float bg[4];
  #pragma unroll
  for (int t = 0; t < 4; t++)
    bg[t] = jval ? ldf(bias, t*50 + jown, f32in) : 0.f;

  // ---- dense W1 fragments + b1/W2 ----
  s16x8 w1f[4][2];
  float b1v[4], w2v[4];
  #pragma unroll
  for (int nt = 0; nt < 4; nt++){
    int c = nt*16 + (ln & 15);
    b1v[nt] = (c < 50) ? ldf(b1, c, f32in) : 0.f;
    w2v[nt] = (c < 50) ? ldf(W2, c, f32in) : 0.f;
    #pragma unroll
    for (int kt = 0; kt < 2; kt++){
      s16x8 v;
      #pragma unroll
      for (int j = 0; j < 8; j++){
        int k = kt*32 + ((ln >> 4) << 3) + j;
        v[j] = (short)((k < 50 && c < 50) ? f2bf(ldf(W1, k*50 + c, f32in)) : (u16)0);
      }
      w1f[nt][kt] = v;
    }
  }
  const float b2s = ldf(b2, 0, f32in);

  const int gr = tid / 50, gj = tid - gr*50;      // gather threads 0..199
  const int foff = (gj >> 5)*512 + (gr + (((gj & 31) >> 3) << 4))*8 + (gj & 7);

  // ---- gate split (R23): q=0 rows{0,1}, q=1 rows{4,5}, q=2 rows{2,3},
  // q=3 rows{6,7}; acc[2],acc[3] arrive via one shfl_xor(32) stage.
  const int q  = ln >> 4;
  const int hi = q >> 1;
  const int rowbase = (q & 1)*4 + hi*2;
  float creg[2] = {0.f, 0.f};
  const int eo16 = ((jown & 31) >> 3) << 4;
  const int aoff0 = (jown >> 5)*512 + (rowbase + eo16)*8 + (jown & 7);

  auto dense_head = [&](int tcd){
    #pragma unroll
    for (int p = 0; p < 2; p++){
      const int mt = 2*wv + p;
      s16x8 a0 = *(const s16x8*)&hbuf[mt][0][ln*8];
      s16x8 a1 = *(const s16x8*)&hbuf[mt][1][ln*8];
      #pragma unroll
      for (int nt = 0; nt < 4; nt++){             // d1 = relu(h@W1+b1)
        f32x4 acc = {0.f,0.f,0.f,0.f};
        acc = mf(a0, w1f[nt][0], acc);
        acc = mf(a1, w1f[nt][1], acc);
        int c = nt*16 + (ln & 15);
        #pragma unroll
        for (int r = 0; r < 4; r++){
          float v = fmaxf(acc[r] + b1v[nt], 0.f);
          int row16 = ((ln >> 4) << 2) + r;
          dwork[wv][c >> 5][(row16 + (((c & 31) >> 3) << 4))*8 + (c & 7)] = f2bf(v);
        }
      }
      s16x8 d0 = *(const s16x8*)&dwork[wv][0][ln*8];
      s16x8 d1 = *(const s16x8*)&dwork[wv][1][ln*8];
      float part[4] = {0.f,0.f,0.f,0.f};
      #pragma unroll
      for (int nt = 0; nt < 4; nt++){             // d2 = relu(d1@W1+b1) . W2
        f32x4 acc = {0.f,0.f,0.f,0.f};
        acc = mf(d0, w1f[nt][0], acc);
        acc = mf(d1, w1f[nt][1], acc);
        #pragma unroll
        for (int r = 0; r < 4; r++)
          part[r] += fmaxf(acc[r] + b1v[nt], 0.f) * w2v[nt];
      }
      #pragma unroll
      for (int d = 1; d < 16; d <<= 1)
        #pragma unroll
        for (int r = 0; r < 4; r++) part[r] += __shfl_xor(part[r], d, 16);
      if ((ln & 15) == 0){
        int qq = ln >> 4;
        #pragma unroll
        for (int r = 0; r < 4; r++){
          int m = mt*16 + (qq << 2) + r;
          int sl8 = m >> 3, rb = m & 7;
          float z = part[r] + b2s;
          z = fmaxf(fminf(z, 1.0f), -1.0f);       // safety clamp
          out[(r0 + rb)*256 + tcd + sl8] = sigm_f(z);
        }
      }
    }
  };

  // ---- prologue: issue chunk-0 gather loads into registers ----
  float ev[32];
  if (tid < 200){
    #pragma unroll
    for (int sl = 0; sl < 16; sl++){
      ev[sl]      = ldf(emb, tokl[sl*8 + gr]*50 + gj, f32in);
      ev[16 + sl] = ldf(emb, tokl[sl*8 + gr + 4]*50 + gj, f32in);
    }
  }

  for (int ch = 0; ch < 16; ch++){
    const int tc = ch*16;
    const int eb = ch & 1;

    // ---- write ering[eb] from regs (loaded during prev chunk) ----
    if (tid < 200){
      #pragma unroll
      for (int sl = 0; sl < 16; sl++)
        ering[eb][sl][foff]      = f2bf(ev[sl]);
      #pragma unroll
      for (int sl = 0; sl < 16; sl++)
        ering[eb][sl][foff + 32] = f2bf(ev[16 + sl]);    // rows 4..7
      // issue NEXT chunk's gather loads (latency hides under the steps)
      if (ch < 15){
        const int tn = tc + 16;
        #pragma unroll
        for (int sl = 0; sl < 16; sl++){
          ev[sl]      = ldf(emb, tokl[(tn + sl)*8 + gr]*50 + gj, f32in);
          ev[16 + sl] = ldf(emb, tokl[(tn + sl)*8 + gr + 4]*50 + gj, f32in);
        }
      }
    }
    if (ch > 0) dense_head(tc - 16);    // prev chunk's head, off the chain
    __syncthreads();                     // ering[eb] ready; hbuf consumed

    // ---- e-frags + e-part accumulators for sl=0 ----
    s16x8 e0 = *(const s16x8*)&ering[eb][0][ln*8];
    s16x8 e1 = *(const s16x8*)&ering[eb][0][512 + ln*8];
    f32x4 ae[4];
    #pragma unroll
    for (int t = 0; t < 4; t++){
      f32x4 a = {0.f,0.f,0.f,0.f};
      a = mf(e0, bz[t][2], a);
      a = mf(e1, bz[t][3], a);
      ae[t] = a;
    }

    for (int sl = 0; sl < 16; sl++){
      const int s   = tc + sl;
      const int cur = s & 1, nxt = cur ^ 1;

      // ---- post-barrier chain: 2-dep h-MFMA + add of precomputed ae ----
      s16x8 av0 = *(const s16x8*)&abuf[cur][ln*8];
      s16x8 av1 = *(const s16x8*)&abuf[cur][512 + ln*8];
      f32x4 g4[4];
      #pragma unroll
      for (int t = 0; t < 4; t++){
        f32x4 a = {0.f,0.f,0.f,0.f};
        a = mf(av0, bz[t][0], a);
        a = mf(av1, bz[t][1], a);
        g4[t] = a + ae[t];
      }

      // ---- redistribute rows 2,3 to q+2 lanes; 2 rows per lane ----
      float zz[4][2];
      #pragma unroll
      for (int t = 0; t < 4; t++){
        float s2 = __shfl_xor(g4[t][2], 32);
        float s3 = __shfl_xor(g4[t][3], 32);
        zz[t][0] = hi ? s2 : g4[t][0];
        zz[t][1] = hi ? s3 : g4[t][1];
      }

      // ---- gates in-register, 2 rows per lane ----
      u16 hb[2];
      #pragma unroll
      for (int rp = 0; rp < 2; rp++){
        float iv = sigm_f(zz[0][rp] + bg[0]);
        float fv = sigm_f(zz[1][rp] + bg[1]);
        float gv = tanh_f(zz[2][rp] + bg[2]);
        float ov = sigm_f(zz[3][rp] + bg[3]);
        float c  = fv * creg[rp] + iv * gv;
        creg[rp] = c;
        hb[rp] = f2bf(ov * tanh_f(c));
      }
      if (jval){
        #pragma unroll
        for (int rp = 0; rp < 2; rp++){
          abuf[nxt][aoff0 + rp*8] = hb[rp];
          int m = sl*8 + rowbase + rp;
          hbuf[m >> 4][jown >> 5][((m & 15) + eo16)*8 + (jown & 7)] = hb[rp];
        }
      }

      // ---- pre-barrier: next step's e-frags + e-part MFMAs (off-chain) ----
      if (sl < 15){
        e0 = *(const s16x8*)&ering[eb][sl + 1][ln*8];
        e1 = *(const s16x8*)&ering[eb][sl + 1][512 + ln*8];
        #pragma unroll
        for (int t = 0; t < 4; t++){
          f32x4 a = {0.f,0.f,0.f,0.f};
          a = mf(e0, bz[t][2], a);
          a = mf(e1, bz[t][3], a);
          ae[t] = a;
        }
      }
      __syncthreads();   // h[nxt] complete -> next step may read
    }
  }

  dense_head(240);                       // last chunk's head
}

extern "C" void kernel_launch(void* const* d_in, const int* in_sizes, int n_in,
                              void* d_out, int out_size, void* d_ws, size_t ws_size,
                              hipStream_t stream) {
  (void)in_sizes; (void)n_in; (void)out_size; (void)d_ws; (void)ws_size;
  hipLaunchKernelGGL(LSTM_Seq2Dis_15272903704706_kernel,
                     dim3(256), dim3(TPB), 0, stream,
                     (const int*)d_in[0], d_in[1], d_in[2], d_in[3], d_in[4],
                     d_in[5], d_in[6], d_in[7], d_in[8], (float*)d_out);
}

// Round 8
// 293.170 us; speedup vs baseline: 1.6467x; 1.0430x over previous
//

#include <hip/hip_runtime.h>

// R26 = R25 light structure (verified 246us; R23 242us) re-balanced for
// OVERLAP + TRANS-HALVING. R25 post-mortem: off-chain moves netted 0 —
// vmcnt(0) drain at barriers nullified the gather prefetch; residual is a
// ~2300cy/step wall with ~320cy trans-pipe issue (10 exp + 10 rcp per lane,
// quarter-rate pipe) and ZERO stall overlap at 1 wave/SIMD. Fix:
//  1. RPB 8->4, grid 512, 2 blocks/CU (launch_bounds(256,2); LDS ~56KB via
//     single ering). Independent blocks interleave on each SIMD: one
//     block's barrier/LDS/trans stalls fill with the other's work. The old
//     R19/R21 dual-block test was on the HEAVY zl structure; this is the
//     light one where stalls dominate.
//  2. Gate cells 2->1 per lane: rows 0..3 fanned to lane groups q=0..3 via
//     2x shfl_xor(32) + 1x shfl_xor(16) per tile. Trans per step halves.
// Per-(row,unit) math bit-identical -> absmax 0.00390625 expected.

typedef unsigned short u16;
typedef unsigned int   u32;
typedef float f32x4 __attribute__((ext_vector_type(4)));
typedef short s16x8 __attribute__((ext_vector_type(8)));

__device__ __forceinline__ float bf2f(u16 u){
  union { u32 i; float f; } v; v.i = ((u32)u) << 16; return v.f;
}
__device__ __forceinline__ u16 f2bf(float f){
  union { float fl; u32 i; } v; v.fl = f;
  u32 r = v.i + 0x7fffu + ((v.i >> 16) & 1u);   // RNE
  return (u16)(r >> 16);
}
__device__ __forceinline__ float frcp(float x){ return __builtin_amdgcn_rcpf(x); }
__device__ __forceinline__ float sigm_f(float x){          // fast sigmoid
  float e = __expf(-x);
  return frcp(1.f + e);
}
__device__ __forceinline__ float tanh_f(float x){          // fast tanh, clamped
  x = fminf(fmaxf(x, -15.f), 15.f);
  float e = __expf(-2.f * x);
  return (1.f - e) * frcp(1.f + e);
}
__device__ __forceinline__ f32x4 mf(s16x8 a, s16x8 b, f32x4 c){
  return __builtin_amdgcn_mfma_f32_16x16x32_bf16(a, b, c, 0, 0, 0);
}
__device__ __forceinline__ float ldf(const void* p, int i, bool f32in){
  if (f32in) return ((const float*)p)[i];
  return bf2f(((const u16*)p)[i]);
}

#define TPB 256
#define RPB 4      // batch rows per block -> 512 blocks, 2 blocks/CU

extern "C" __global__ __launch_bounds__(TPB, 2) void LSTM_Seq2Dis_15272903704706_kernel(
    const int* idx, const void* emb, const void* Wk, const void* Uk,
    const void* bias, const void* W1, const void* b1,
    const void* W2, const void* b2, float* out)
{
  __shared__ __align__(16) u16 ering[16][1024];   // e frags per chunk step (32 KB)
  __shared__ __align__(16) u16 abuf[2][1024];     // h frags, double buffer (4 KB)
  __shared__ __align__(16) u16 hbuf[4][2][512];   // chunk h for dense head (8 KB)
  __shared__ __align__(16) u16 dwork[4][2][512];  // per-wave d1 scratch (8 KB)
  __shared__ int   tokl[1024];                    // token ids [s][r], r 0..3 (4 KB)
  __shared__ int   s_f32;

  const int tid = threadIdx.x;
  const int wv  = tid >> 6, ln = tid & 63;
  const int r0  = blockIdx.x * RPB;

  if (tid == 0){
    const u32* ew = (const u32*)emb;
    int hits = 0;
    for (int i = 0; i < 64; i++){
      u32 ef = (ew[i] >> 7) & 0xFFu;
      if (ef >= 112u && ef <= 127u) hits++;
    }
    s_f32 = (hits < 32) ? 1 : 0;
  }

  for (int i = tid; i < 16*1024; i += TPB) ((u16*)ering)[i] = 0;
  for (int i = tid; i < 2*1024;  i += TPB) ((u16*)abuf)[i]  = 0;
  for (int i = tid; i < 4*2*512; i += TPB) ((u16*)hbuf)[i]  = 0;
  for (int i = tid; i < 1024;    i += TPB){
    int r = i & 3, s = i >> 2;
    tokl[i] = idx[(r0 + r)*256 + s];
  }
  __syncthreads();
  const bool f32in = (s_f32 != 0);

  // ---- z-GEMM B-frags, GATE-MAJOR cols (R22/R23-verified): lane owns unit
  // jown = wv*16 + (ln&15); tile t = gate t, B col = t*50 + jown.
  const int jown = wv*16 + (ln & 15);
  const bool jval = (jown < 50);
  s16x8 bz[4][4];
  #pragma unroll
  for (int t = 0; t < 4; t++){
    const int col = t*50 + jown;
    #pragma unroll
    for (int kt = 0; kt < 4; kt++){
      s16x8 v;
      #pragma unroll
      for (int j = 0; j < 8; j++){
        int k = kt*32 + ((ln >> 4) << 3) + j;
        float w = 0.f;
        if (jval){
          if (k < 50)                  w = ldf(Uk, k*200 + col, f32in);
          else if (k >= 64 && k < 114) w = ldf(Wk, (k-64)*200 + col, f32in);
        }
        v[j] = (short)f2bf(w);
      }
      bz[t][kt] = v;
    }
  }
  float bg[4];
  #pragma unroll
  for (int t = 0; t < 4; t++)
    bg[t] = jval ? ldf(bias, t*50 + jown, f32in) : 0.f;

  // ---- dense W1 fragments + b1/W2 ----
  s16x8 w1f[4][2];
  float b1v[4], w2v[4];
  #pragma unroll
  for (int nt = 0; nt < 4; nt++){
    int c = nt*16 + (ln & 15);
    b1v[nt] = (c < 50) ? ldf(b1, c, f32in) : 0.f;
    w2v[nt] = (c < 50) ? ldf(W2, c, f32in) : 0.f;
    #pragma unroll
    for (int kt = 0; kt < 2; kt++){
      s16x8 v;
      #pragma unroll
      for (int j = 0; j < 8; j++){
        int k = kt*32 + ((ln >> 4) << 3) + j;
        v[j] = (short)((k < 50 && c < 50) ? f2bf(ldf(W1, k*50 + c, f32in)) : (u16)0);
      }
      w1f[nt][kt] = v;
    }
  }
  const float b2s = ldf(b2, 0, f32in);

  const int gr = tid / 50, gj = tid - gr*50;      // gather threads 0..199, gr 0..3
  const int foff = (gj >> 5)*512 + (gr + (((gj & 31) >> 3) << 4))*8 + (gj & 7);

  // ---- gate spread: lane group q handles row q (1 cell/lane) ----
  const int q  = ln >> 4;
  const int hi = q >> 1;
  float creg = 0.f;                                // cell state (row q, unit jown)
  const int eo16 = ((jown & 31) >> 3) << 4;
  const int aoff = (jown >> 5)*512 + (q + eo16)*8 + (jown & 7);

  auto dense_head = [&](int tcd){
    const int mt = wv;                             // 64 m-rows -> 1 tile/wave
    s16x8 a0 = *(const s16x8*)&hbuf[mt][0][ln*8];
    s16x8 a1 = *(const s16x8*)&hbuf[mt][1][ln*8];
    #pragma unroll
    for (int nt = 0; nt < 4; nt++){                // d1 = relu(h@W1+b1)
      f32x4 acc = {0.f,0.f,0.f,0.f};
      acc = mf(a0, w1f[nt][0], acc);
      acc = mf(a1, w1f[nt][1], acc);
      int c = nt*16 + (ln & 15);
      #pragma unroll
      for (int r = 0; r < 4; r++){
        float v = fmaxf(acc[r] + b1v[nt], 0.f);
        int row16 = ((ln >> 4) << 2) + r;
        dwork[wv][c >> 5][(row16 + (((c & 31) >> 3) << 4))*8 + (c & 7)] = f2bf(v);
      }
    }
    s16x8 d0 = *(const s16x8*)&dwork[wv][0][ln*8];
    s16x8 d1 = *(const s16x8*)&dwork[wv][1][ln*8];
    float part[4] = {0.f,0.f,0.f,0.f};
    #pragma unroll
    for (int nt = 0; nt < 4; nt++){                // d2 = relu(d1@W1+b1) . W2
      f32x4 acc = {0.f,0.f,0.f,0.f};
      acc = mf(d0, w1f[nt][0], acc);
      acc = mf(d1, w1f[nt][1], acc);
      #pragma unroll
      for (int r = 0; r < 4; r++)
        part[r] += fmaxf(acc[r] + b1v[nt], 0.f) * w2v[nt];
    }
    #pragma unroll
    for (int d = 1; d < 16; d <<= 1)
      #pragma unroll
      for (int r = 0; r < 4; r++) part[r] += __shfl_xor(part[r], d, 16);
    if ((ln & 15) == 0){
      int qq = ln >> 4;
      #pragma unroll
      for (int r = 0; r < 4; r++){
        int m = mt*16 + (qq << 2) + r;
        int sl4 = m >> 2, rb = m & 3;
        float z = part[r] + b2s;
        z = fmaxf(fminf(z, 1.0f), -1.0f);          // safety clamp
        out[(r0 + rb)*256 + tcd + sl4] = sigm_f(z);
      }
    }
  };

  // ---- prologue: issue chunk-0 gather loads into registers ----
  float ev[16];
  if (tid < 200){
    #pragma unroll
    for (int sl = 0; sl < 16; sl++)
      ev[sl] = ldf(emb, tokl[sl*4 + gr]*50 + gj, f32in);
  }

  for (int ch = 0; ch < 16; ch++){
    const int tc = ch*16;

    // ---- write ering from regs; issue next chunk's loads; head off-chain ----
    if (tid < 200){
      #pragma unroll
      for (int sl = 0; sl < 16; sl++)
        ering[sl][foff] = f2bf(ev[sl]);
      if (ch < 15){
        const int tn = tc + 16;
        #pragma unroll
        for (int sl = 0; sl < 16; sl++)
          ev[sl] = ldf(emb, tokl[(tn + sl)*4 + gr]*50 + gj, f32in);
      }
    }
    if (ch > 0) dense_head(tc - 16);    // prev chunk's head, off the chain
    __syncthreads();                     // ering ready; hbuf consumed

    // ---- e-frags + e-part accumulators for sl=0 (split-K, off-chain) ----
    s16x8 e0 = *(const s16x8*)&ering[0][ln*8];
    s16x8 e1 = *(const s16x8*)&ering[0][512 + ln*8];
    f32x4 ae[4];
    #pragma unroll
    for (int t = 0; t < 4; t++){
      f32x4 a = {0.f,0.f,0.f,0.f};
      a = mf(e0, bz[t][2], a);
      a = mf(e1, bz[t][3], a);
      ae[t] = a;
    }

    for (int sl = 0; sl < 16; sl++){
      const int s   = tc + sl;
      const int cur = s & 1, nxt = cur ^ 1;

      // ---- post-barrier chain: 2-dep h-MFMA + add of precomputed ae ----
      s16x8 av0 = *(const s16x8*)&abuf[cur][ln*8];
      s16x8 av1 = *(const s16x8*)&abuf[cur][512 + ln*8];
      f32x4 g4[4];
      #pragma unroll
      for (int t = 0; t < 4; t++){
        f32x4 a = {0.f,0.f,0.f,0.f};
        a = mf(av0, bz[t][0], a);
        a = mf(av1, bz[t][1], a);
        g4[t] = a + ae[t];
      }

      // ---- fan rows 0..3 to lane groups q=0..3 (1 cell/lane) ----
      // stage1 (xor 32): q0's g[2],g[3] -> q2;  stage2 (xor 16): row1->q1, row3->q3
      float cell[4];
      #pragma unroll
      for (int t = 0; t < 4; t++){
        float s2  = __shfl_xor(g4[t][2], 32);
        float s3  = __shfl_xor(g4[t][3], 32);
        float zz0 = hi ? s2 : g4[t][0];
        float zz1 = hi ? s3 : g4[t][1];
        float w   = __shfl_xor(zz1, 16);
        cell[t]   = (q & 1) ? w : zz0;
      }

      // ---- gates in-register, 1 cell per lane (row q, unit jown) ----
      float iv = sigm_f(cell[0] + bg[0]);
      float fv = sigm_f(cell[1] + bg[1]);
      float gv = tanh_f(cell[2] + bg[2]);
      float ov = sigm_f(cell[3] + bg[3]);
      float c  = fv * creg + iv * gv;
      creg = c;
      u16 hb = f2bf(ov * tanh_f(c));
      if (jval){
        abuf[nxt][aoff] = hb;
        int m = sl*4 + q;
        hbuf[m >> 4][jown >> 5][((m & 15) + eo16)*8 + (jown & 7)] = hb;
      }

      // ---- pre-barrier: next step's e-frags + e-part MFMAs (off-chain) ----
      if (sl < 15){
        e0 = *(const s16x8*)&ering[sl + 1][ln*8];
        e1 = *(const s16x8*)&ering[sl + 1][512 + ln*8];
        #pragma unroll
        for (int t = 0; t < 4; t++){
          f32x4 a = {0.f,0.f,0.f,0.f};
          a = mf(e0, bz[t][2], a);
          a = mf(e1, bz[t][3], a);
          ae[t] = a;
        }
      }
      __syncthreads();   // h[nxt] complete -> next step may read
    }
  }

  dense_head(240);                       // last chunk's head
}

extern "C" void kernel_launch(void* const* d_in, const int* in_sizes, int n_in,
                              void* d_out, int out_size, void* d_ws, size_t ws_size,
                              hipStream_t stream) {
  (void)in_sizes; (void)n_in; (void)out_size; (void)d_ws; (void)ws_size;
  hipLaunchKernelGGL(LSTM_Seq2Dis_15272903704706_kernel,
                     dim3(512), dim3(TPB), 0, stream,
                     (const int*)d_in[0], d_in[1], d_in[2], d_in[3], d_in[4],
                     d_in[5], d_in[6], d_in[7], d_in[8], (float*)d_out);
}

// Round 9
// 288.502 us; speedup vs baseline: 1.6734x; 1.0162x over previous
//

#include <hip/hip_runtime.h>

// R27 = R26 (verified 239.6us best-dispatch, absmax 0.0039) + two ON-CHAIN
// cuts, zero math changes. R26 post-mortem: 2 blocks/CU doubled Occ and
// MfmaUtil but wall unchanged -> TLP can't shorten a latency-bound serial
// chain; only on-chain cuts count (also rules out 2-chain pipelining:
// 2*max(G,Z)+2B >= G+Z+B always).
//  1. Raw barriers: this kernel's cross-thread data flows ONLY through LDS;
//     replace __syncthreads (s_waitcnt vmcnt(0) lgkmcnt(0) + s_barrier) with
//     "s_waitcnt lgkmcnt(0); s_barrier". The vmcnt(0) drain was serializing
//     the 16-load embedding prefetch at the chunk-start barrier (why R25's
//     T14 prefetch measured neutral). Loads now ride under the 16 steps.
//  2. Drop abuf: h A-frags read directly from hbuf (prev = (sl+15)&15;
//     addr = ln*8 + (prev&3)*32 within tile prev>>2). One ds_write less on
//     the chain, -4KB LDS. A-rows 4..15 read neighboring steps' h = finite
//     garbage in discarded C rows.
// Values bit-identical -> absmax 0.00390625 expected exactly.

typedef unsigned short u16;
typedef unsigned int   u32;
typedef float f32x4 __attribute__((ext_vector_type(4)));
typedef short s16x8 __attribute__((ext_vector_type(8)));

// LDS-only workgroup barrier: waits local ops, does NOT drain vmcnt.
#define WGBAR() asm volatile("s_waitcnt lgkmcnt(0)\n\ts_barrier" ::: "memory")

__device__ __forceinline__ float bf2f(u16 u){
  union { u32 i; float f; } v; v.i = ((u32)u) << 16; return v.f;
}
__device__ __forceinline__ u16 f2bf(float f){
  union { float fl; u32 i; } v; v.fl = f;
  u32 r = v.i + 0x7fffu + ((v.i >> 16) & 1u);   // RNE
  return (u16)(r >> 16);
}
__device__ __forceinline__ float frcp(float x){ return __builtin_amdgcn_rcpf(x); }
__device__ __forceinline__ float sigm_f(float x){          // fast sigmoid
  float e = __expf(-x);
  return frcp(1.f + e);
}
__device__ __forceinline__ float tanh_f(float x){          // fast tanh, clamped
  x = fminf(fmaxf(x, -15.f), 15.f);
  float e = __expf(-2.f * x);
  return (1.f - e) * frcp(1.f + e);
}
__device__ __forceinline__ f32x4 mf(s16x8 a, s16x8 b, f32x4 c){
  return __builtin_amdgcn_mfma_f32_16x16x32_bf16(a, b, c, 0, 0, 0);
}
__device__ __forceinline__ float ldf(const void* p, int i, bool f32in){
  if (f32in) return ((const float*)p)[i];
  return bf2f(((const u16*)p)[i]);
}

#define TPB 256
#define RPB 4      // batch rows per block -> 512 blocks, 2 blocks/CU

extern "C" __global__ __launch_bounds__(TPB, 2) void LSTM_Seq2Dis_15272903704706_kernel(
    const int* idx, const void* emb, const void* Wk, const void* Uk,
    const void* bias, const void* W1, const void* b1,
    const void* W2, const void* b2, float* out)
{
  __shared__ __align__(16) u16 ering[16][1024];   // e frags per chunk step (32 KB)
  __shared__ __align__(16) u16 hbuf[4][2][512];   // chunk h: dense head + A-frags (8 KB)
  __shared__ __align__(16) u16 dwork[4][2][512];  // per-wave d1 scratch (8 KB)
  __shared__ int   tokl[1024];                    // token ids [s][r], r 0..3 (4 KB)
  __shared__ int   s_f32;

  const int tid = threadIdx.x;
  const int wv  = tid >> 6, ln = tid & 63;
  const int r0  = blockIdx.x * RPB;

  if (tid == 0){
    const u32* ew = (const u32*)emb;
    int hits = 0;
    for (int i = 0; i < 64; i++){
      u32 ef = (ew[i] >> 7) & 0xFFu;
      if (ef >= 112u && ef <= 127u) hits++;
    }
    s_f32 = (hits < 32) ? 1 : 0;
  }

  for (int i = tid; i < 16*1024; i += TPB) ((u16*)ering)[i] = 0;
  for (int i = tid; i < 4*2*512; i += TPB) ((u16*)hbuf)[i]  = 0;
  for (int i = tid; i < 1024;    i += TPB){
    int r = i & 3, s = i >> 2;
    tokl[i] = idx[(r0 + r)*256 + s];
  }
  __syncthreads();
  const bool f32in = (s_f32 != 0);

  // ---- z-GEMM B-frags, GATE-MAJOR cols (R22/R23-verified): lane owns unit
  // jown = wv*16 + (ln&15); tile t = gate t, B col = t*50 + jown.
  const int jown = wv*16 + (ln & 15);
  const bool jval = (jown < 50);
  s16x8 bz[4][4];
  #pragma unroll
  for (int t = 0; t < 4; t++){
    const int col = t*50 + jown;
    #pragma unroll
    for (int kt = 0; kt < 4; kt++){
      s16x8 v;
      #pragma unroll
      for (int j = 0; j < 8; j++){
        int k = kt*32 + ((ln >> 4) << 3) + j;
        float w = 0.f;
        if (jval){
          if (k < 50)                  w = ldf(Uk, k*200 + col, f32in);
          else if (k >= 64 && k < 114) w = ldf(Wk, (k-64)*200 + col, f32in);
        }
        v[j] = (short)f2bf(w);
      }
      bz[t][kt] = v;
    }
  }
  float bg[4];
  #pragma unroll
  for (int t = 0; t < 4; t++)
    bg[t] = jval ? ldf(bias, t*50 + jown, f32in) : 0.f;

  // ---- dense W1 fragments + b1/W2 ----
  s16x8 w1f[4][2];
  float b1v[4], w2v[4];
  #pragma unroll
  for (int nt = 0; nt < 4; nt++){
    int c = nt*16 + (ln & 15);
    b1v[nt] = (c < 50) ? ldf(b1, c, f32in) : 0.f;
    w2v[nt] = (c < 50) ? ldf(W2, c, f32in) : 0.f;
    #pragma unroll
    for (int kt = 0; kt < 2; kt++){
      s16x8 v;
      #pragma unroll
      for (int j = 0; j < 8; j++){
        int k = kt*32 + ((ln >> 4) << 3) + j;
        v[j] = (short)((k < 50 && c < 50) ? f2bf(ldf(W1, k*50 + c, f32in)) : (u16)0);
      }
      w1f[nt][kt] = v;
    }
  }
  const float b2s = ldf(b2, 0, f32in);

  const int gr = tid / 50, gj = tid - gr*50;      // gather threads 0..199, gr 0..3
  const int foff = (gj >> 5)*512 + (gr + (((gj & 31) >> 3) << 4))*8 + (gj & 7);

  // ---- gate spread (R26): lane group q handles row q (1 cell/lane) ----
  const int q  = ln >> 4;
  const int hi = q >> 1;
  float creg = 0.f;                                // cell state (row q, unit jown)
  const int eo16 = ((jown & 31) >> 3) << 4;

  auto dense_head = [&](int tcd){
    const int mt = wv;                             // 64 m-rows -> 1 tile/wave
    s16x8 a0 = *(const s16x8*)&hbuf[mt][0][ln*8];
    s16x8 a1 = *(const s16x8*)&hbuf[mt][1][ln*8];
    #pragma unroll
    for (int nt = 0; nt < 4; nt++){                // d1 = relu(h@W1+b1)
      f32x4 acc = {0.f,0.f,0.f,0.f};
      acc = mf(a0, w1f[nt][0], acc);
      acc = mf(a1, w1f[nt][1], acc);
      int c = nt*16 + (ln & 15);
      #pragma unroll
      for (int r = 0; r < 4; r++){
        float v = fmaxf(acc[r] + b1v[nt], 0.f);
        int row16 = ((ln >> 4) << 2) + r;
        dwork[wv][c >> 5][(row16 + (((c & 31) >> 3) << 4))*8 + (c & 7)] = f2bf(v);
      }
    }
    s16x8 d0 = *(const s16x8*)&dwork[wv][0][ln*8];
    s16x8 d1 = *(const s16x8*)&dwork[wv][1][ln*8];
    float part[4] = {0.f,0.f,0.f,0.f};
    #pragma unroll
    for (int nt = 0; nt < 4; nt++){                // d2 = relu(d1@W1+b1) . W2
      f32x4 acc = {0.f,0.f,0.f,0.f};
      acc = mf(d0, w1f[nt][0], acc);
      acc = mf(d1, w1f[nt][1], acc);
      #pragma unroll
      for (int r = 0; r < 4; r++)
        part[r] += fmaxf(acc[r] + b1v[nt], 0.f) * w2v[nt];
    }
    #pragma unroll
    for (int d = 1; d < 16; d <<= 1)
      #pragma unroll
      for (int r = 0; r < 4; r++) part[r] += __shfl_xor(part[r], d, 16);
    if ((ln & 15) == 0){
      int qq = ln >> 4;
      #pragma unroll
      for (int r = 0; r < 4; r++){
        int m = mt*16 + (qq << 2) + r;
        int sl4 = m >> 2, rb = m & 3;
        float z = part[r] + b2s;
        z = fmaxf(fminf(z, 1.0f), -1.0f);          // safety clamp
        out[(r0 + rb)*256 + tcd + sl4] = sigm_f(z);
      }
    }
  };

  // ---- prologue: issue chunk-0 gather loads into registers ----
  float ev[16];
  if (tid < 200){
    #pragma unroll
    for (int sl = 0; sl < 16; sl++)
      ev[sl] = ldf(emb, tokl[sl*4 + gr]*50 + gj, f32in);
  }

  for (int ch = 0; ch < 16; ch++){
    const int tc = ch*16;

    // ---- write ering from regs; issue next chunk's loads; head off-chain ----
    if (tid < 200){
      #pragma unroll
      for (int sl = 0; sl < 16; sl++)
        ering[sl][foff] = f2bf(ev[sl]);
      if (ch < 15){
        const int tn = tc + 16;
        #pragma unroll
        for (int sl = 0; sl < 16; sl++)
          ev[sl] = ldf(emb, tokl[(tn + sl)*4 + gr]*50 + gj, f32in);
      }
    }
    if (ch > 0) dense_head(tc - 16);    // prev chunk's head, off the chain
    WGBAR();                             // ering ready; hbuf consumed (LDS only)

    // ---- e-frags + e-part accumulators for sl=0 (split-K, off-chain) ----
    s16x8 e0 = *(const s16x8*)&ering[0][ln*8];
    s16x8 e1 = *(const s16x8*)&ering[0][512 + ln*8];
    f32x4 ae[4];
    #pragma unroll
    for (int t = 0; t < 4; t++){
      f32x4 a = {0.f,0.f,0.f,0.f};
      a = mf(e0, bz[t][2], a);
      a = mf(e1, bz[t][3], a);
      ae[t] = a;
    }

    for (int sl = 0; sl < 16; sl++){
      // ---- A-frags straight from hbuf (h written at step sl-1) ----
      const int prev = (sl + 15) & 15;
      const int aoffr = ln*8 + (prev & 3)*32;
      s16x8 av0 = *(const s16x8*)&hbuf[prev >> 2][0][aoffr];
      s16x8 av1 = *(const s16x8*)&hbuf[prev >> 2][1][aoffr];
      f32x4 g4[4];
      #pragma unroll
      for (int t = 0; t < 4; t++){
        f32x4 a = {0.f,0.f,0.f,0.f};
        a = mf(av0, bz[t][0], a);
        a = mf(av1, bz[t][1], a);
        g4[t] = a + ae[t];
      }

      // ---- fan rows 0..3 to lane groups q=0..3 (1 cell/lane) ----
      float cell[4];
      #pragma unroll
      for (int t = 0; t < 4; t++){
        float s2  = __shfl_xor(g4[t][2], 32);
        float s3  = __shfl_xor(g4[t][3], 32);
        float zz0 = hi ? s2 : g4[t][0];
        float zz1 = hi ? s3 : g4[t][1];
        float w   = __shfl_xor(zz1, 16);
        cell[t]   = (q & 1) ? w : zz0;
      }

      // ---- gates in-register, 1 cell per lane (row q, unit jown) ----
      float iv = sigm_f(cell[0] + bg[0]);
      float fv = sigm_f(cell[1] + bg[1]);
      float gv = tanh_f(cell[2] + bg[2]);
      float ov = sigm_f(cell[3] + bg[3]);
      float c  = fv * creg + iv * gv;
      creg = c;
      u16 hb = f2bf(ov * tanh_f(c));
      if (jval){
        int m = sl*4 + q;
        hbuf[m >> 2 >> 2][jown >> 5][((m & 15) + eo16)*8 + (jown & 7)] = hb;
      }

      // ---- pre-barrier: next step's e-frags + e-part MFMAs (off-chain) ----
      if (sl < 15){
        e0 = *(const s16x8*)&ering[sl + 1][ln*8];
        e1 = *(const s16x8*)&ering[sl + 1][512 + ln*8];
        #pragma unroll
        for (int t = 0; t < 4; t++){
          f32x4 a = {0.f,0.f,0.f,0.f};
          a = mf(e0, bz[t][2], a);
          a = mf(e1, bz[t][3], a);
          ae[t] = a;
        }
      }
      WGBAR();           // h visible -> next step may read (LDS only)
    }
  }

  dense_head(240);                       // last chunk's head
}

extern "C" void kernel_launch(void* const* d_in, const int* in_sizes, int n_in,
                              void* d_out, int out_size, void* d_ws, size_t ws_size,
                              hipStream_t stream) {
  (void)in_sizes; (void)n_in; (void)out_size; (void)d_ws; (void)ws_size;
  hipLaunchKernelGGL(LSTM_Seq2Dis_15272903704706_kernel,
                     dim3(512), dim3(TPB), 0, stream,
                     (const int*)d_in[0], d_in[1], d_in[2], d_in[3], d_in[4],
                     d_in[5], d_in[6], d_in[7], d_in[8], (float*)d_out);
}

// Round 10
// 286.341 us; speedup vs baseline: 1.6860x; 1.0075x over previous
//

#include <hip/hip_runtime.h>

// R28 = R27 (verified 237us best-dispatch, absmax 0.0039) + two DEPENDENT-
// STAGE deletions. Model fix from R24b/R27: at 1-2 waves/SIMD every
// dependent stage costs full raw latency (~150cy avg); the step is ~15
// stages ~= 2250cy (R24b's barrier-free variant: MORE stages -> 4000cy,
// confirming stages not barriers dominate). Cuts, adding no new stages:
//  1. ae AND gate bias folded into MFMA C-input: g4 = mf(av0,bz0,
//     mf(av1,bz1,ae)); ae = mf(e0,bz2, mf(e1,bz3, bias)) built pre-barrier.
//     Deletes the on-chain "+ae" VALU stage and the bias add (f32 reassoc
//     only, ~1ulp << bf16-h noise).
//  2. Fan 2 stages -> 1: one shfl_xor(32) pair, 2 cells/lane (q0 rows{0,1},
//     q2 rows{2,3}; q1/q3 redundant-garbage, excluded from writes). Deletes
//     the xor16 bperm stage + select; trans issue doubles (indep, pipelined).
// Everything else identical to R27 (WGBAR raw barriers, hbuf-as-A-frag,
// reg-staged gather, off-chain dense head).

typedef unsigned short u16;
typedef unsigned int   u32;
typedef float f32x4 __attribute__((ext_vector_type(4)));
typedef short s16x8 __attribute__((ext_vector_type(8)));

// LDS-only workgroup barrier: waits local ops, does NOT drain vmcnt.
#define WGBAR() asm volatile("s_waitcnt lgkmcnt(0)\n\ts_barrier" ::: "memory")

__device__ __forceinline__ float bf2f(u16 u){
  union { u32 i; float f; } v; v.i = ((u32)u) << 16; return v.f;
}
__device__ __forceinline__ u16 f2bf(float f){
  union { float fl; u32 i; } v; v.fl = f;
  u32 r = v.i + 0x7fffu + ((v.i >> 16) & 1u);   // RNE
  return (u16)(r >> 16);
}
__device__ __forceinline__ float frcp(float x){ return __builtin_amdgcn_rcpf(x); }
__device__ __forceinline__ float sigm_f(float x){          // fast sigmoid
  float e = __expf(-x);
  return frcp(1.f + e);
}
__device__ __forceinline__ float tanh_f(float x){          // fast tanh, clamped
  x = fminf(fmaxf(x, -15.f), 15.f);
  float e = __expf(-2.f * x);
  return (1.f - e) * frcp(1.f + e);
}
__device__ __forceinline__ f32x4 mf(s16x8 a, s16x8 b, f32x4 c){
  return __builtin_amdgcn_mfma_f32_16x16x32_bf16(a, b, c, 0, 0, 0);
}
__device__ __forceinline__ float ldf(const void* p, int i, bool f32in){
  if (f32in) return ((const float*)p)[i];
  return bf2f(((const u16*)p)[i]);
}

#define TPB 256
#define RPB 4      // batch rows per block -> 512 blocks, 2 blocks/CU

extern "C" __global__ __launch_bounds__(TPB, 2) void LSTM_Seq2Dis_15272903704706_kernel(
    const int* idx, const void* emb, const void* Wk, const void* Uk,
    const void* bias, const void* W1, const void* b1,
    const void* W2, const void* b2, float* out)
{
  __shared__ __align__(16) u16 ering[16][1024];   // e frags per chunk step (32 KB)
  __shared__ __align__(16) u16 hbuf[4][2][512];   // chunk h: dense head + A-frags (8 KB)
  __shared__ __align__(16) u16 dwork[4][2][512];  // per-wave d1 scratch (8 KB)
  __shared__ int   tokl[1024];                    // token ids [s][r], r 0..3 (4 KB)
  __shared__ int   s_f32;

  const int tid = threadIdx.x;
  const int wv  = tid >> 6, ln = tid & 63;
  const int r0  = blockIdx.x * RPB;

  if (tid == 0){
    const u32* ew = (const u32*)emb;
    int hits = 0;
    for (int i = 0; i < 64; i++){
      u32 ef = (ew[i] >> 7) & 0xFFu;
      if (ef >= 112u && ef <= 127u) hits++;
    }
    s_f32 = (hits < 32) ? 1 : 0;
  }

  for (int i = tid; i < 16*1024; i += TPB) ((u16*)ering)[i] = 0;
  for (int i = tid; i < 4*2*512; i += TPB) ((u16*)hbuf)[i]  = 0;
  for (int i = tid; i < 1024;    i += TPB){
    int r = i & 3, s = i >> 2;
    tokl[i] = idx[(r0 + r)*256 + s];
  }
  __syncthreads();
  const bool f32in = (s_f32 != 0);

  // ---- z-GEMM B-frags, GATE-MAJOR cols (R22/R23-verified): lane owns unit
  // jown = wv*16 + (ln&15); tile t = gate t, B col = t*50 + jown.
  const int jown = wv*16 + (ln & 15);
  const bool jval = (jown < 50);
  s16x8 bz[4][4];
  #pragma unroll
  for (int t = 0; t < 4; t++){
    const int col = t*50 + jown;
    #pragma unroll
    for (int kt = 0; kt < 4; kt++){
      s16x8 v;
      #pragma unroll
      for (int j = 0; j < 8; j++){
        int k = kt*32 + ((ln >> 4) << 3) + j;
        float w = 0.f;
        if (jval){
          if (k < 50)                  w = ldf(Uk, k*200 + col, f32in);
          else if (k >= 64 && k < 114) w = ldf(Wk, (k-64)*200 + col, f32in);
        }
        v[j] = (short)f2bf(w);
      }
      bz[t][kt] = v;
    }
  }
  f32x4 bgv[4];                                   // bias splat (C-init for ae)
  #pragma unroll
  for (int t = 0; t < 4; t++){
    float b = jval ? ldf(bias, t*50 + jown, f32in) : 0.f;
    bgv[t] = (f32x4){b, b, b, b};
  }

  // ---- dense W1 fragments + b1/W2 ----
  s16x8 w1f[4][2];
  float b1v[4], w2v[4];
  #pragma unroll
  for (int nt = 0; nt < 4; nt++){
    int c = nt*16 + (ln & 15);
    b1v[nt] = (c < 50) ? ldf(b1, c, f32in) : 0.f;
    w2v[nt] = (c < 50) ? ldf(W2, c, f32in) : 0.f;
    #pragma unroll
    for (int kt = 0; kt < 2; kt++){
      s16x8 v;
      #pragma unroll
      for (int j = 0; j < 8; j++){
        int k = kt*32 + ((ln >> 4) << 3) + j;
        v[j] = (short)((k < 50 && c < 50) ? f2bf(ldf(W1, k*50 + c, f32in)) : (u16)0);
      }
      w1f[nt][kt] = v;
    }
  }
  const float b2s = ldf(b2, 0, f32in);

  const int gr = tid / 50, gj = tid - gr*50;      // gather threads 0..199, gr 0..3
  const int foff = (gj >> 5)*512 + (gr + (((gj & 31) >> 3) << 4))*8 + (gj & 7);

  // ---- gate spread (R28): ONE fan stage, 2 cells/lane.
  //   lo half (q0,q1): rows 0,1 from own acc[0],acc[1]
  //   hi half (q2,q3): rows 2,3 via shfl_xor(32) of partner acc[2],acc[3]
  //   q1/q3 are redundant duplicates (same jown as q0/q2) -> excluded from
  //   writes; their inputs are finite (hbuf garbage rows are other steps' h).
  const int q  = ln >> 4;
  const int hi = q >> 1;
  const bool wrt = jval && ((q & 1) == 0);        // one writer per (rowpair,unit)
  float creg[2] = {0.f, 0.f};                     // cell state rows hi*2+{0,1}
  const int eo16 = ((jown & 31) >> 3) << 4;

  auto dense_head = [&](int tcd){
    const int mt = wv;                             // 64 m-rows -> 1 tile/wave
    s16x8 a0 = *(const s16x8*)&hbuf[mt][0][ln*8];
    s16x8 a1 = *(const s16x8*)&hbuf[mt][1][ln*8];
    #pragma unroll
    for (int nt = 0; nt < 4; nt++){                // d1 = relu(h@W1+b1)
      f32x4 acc = {0.f,0.f,0.f,0.f};
      acc = mf(a0, w1f[nt][0], acc);
      acc = mf(a1, w1f[nt][1], acc);
      int c = nt*16 + (ln & 15);
      #pragma unroll
      for (int r = 0; r < 4; r++){
        float v = fmaxf(acc[r] + b1v[nt], 0.f);
        int row16 = ((ln >> 4) << 2) + r;
        dwork[wv][c >> 5][(row16 + (((c & 31) >> 3) << 4))*8 + (c & 7)] = f2bf(v);
      }
    }
    s16x8 d0 = *(const s16x8*)&dwork[wv][0][ln*8];
    s16x8 d1 = *(const s16x8*)&dwork[wv][1][ln*8];
    float part[4] = {0.f,0.f,0.f,0.f};
    #pragma unroll
    for (int nt = 0; nt < 4; nt++){                // d2 = relu(d1@W1+b1) . W2
      f32x4 acc = {0.f,0.f,0.f,0.f};
      acc = mf(d0, w1f[nt][0], acc);
      acc = mf(d1, w1f[nt][1], acc);
      #pragma unroll
      for (int r = 0; r < 4; r++)
        part[r] += fmaxf(acc[r] + b1v[nt], 0.f) * w2v[nt];
    }
    #pragma unroll
    for (int d = 1; d < 16; d <<= 1)
      #pragma unroll
      for (int r = 0; r < 4; r++) part[r] += __shfl_xor(part[r], d, 16);
    if ((ln & 15) == 0){
      int qq = ln >> 4;
      #pragma unroll
      for (int r = 0; r < 4; r++){
        int m = mt*16 + (qq << 2) + r;
        int sl4 = m >> 2, rb = m & 3;
        float z = part[r] + b2s;
        z = fmaxf(fminf(z, 1.0f), -1.0f);          // safety clamp
        out[(r0 + rb)*256 + tcd + sl4] = sigm_f(z);
      }
    }
  };

  // ---- prologue: issue chunk-0 gather loads into registers ----
  float ev[16];
  if (tid < 200){
    #pragma unroll
    for (int sl = 0; sl < 16; sl++)
      ev[sl] = ldf(emb, tokl[sl*4 + gr]*50 + gj, f32in);
  }

  for (int ch = 0; ch < 16; ch++){
    const int tc = ch*16;

    // ---- write ering from regs; issue next chunk's loads; head off-chain ----
    if (tid < 200){
      #pragma unroll
      for (int sl = 0; sl < 16; sl++)
        ering[sl][foff] = f2bf(ev[sl]);
      if (ch < 15){
        const int tn = tc + 16;
        #pragma unroll
        for (int sl = 0; sl < 16; sl++)
          ev[sl] = ldf(emb, tokl[(tn + sl)*4 + gr]*50 + gj, f32in);
      }
    }
    if (ch > 0) dense_head(tc - 16);    // prev chunk's head, off the chain
    WGBAR();                             // ering ready; hbuf consumed (LDS only)

    // ---- sl=0 e-part + bias, folded into C-init (split-K, off-chain) ----
    s16x8 e0 = *(const s16x8*)&ering[0][ln*8];
    s16x8 e1 = *(const s16x8*)&ering[0][512 + ln*8];
    f32x4 ae[4];
    #pragma unroll
    for (int t = 0; t < 4; t++){
      f32x4 a = bgv[t];
      a = mf(e1, bz[t][3], a);
      a = mf(e0, bz[t][2], a);
      ae[t] = a;
    }

    for (int sl = 0; sl < 16; sl++){
      // ---- A-frags straight from hbuf (h written at step sl-1) ----
      const int prev = (sl + 15) & 15;
      const int aoffr = ln*8 + (prev & 3)*32;
      s16x8 av0 = *(const s16x8*)&hbuf[prev >> 2][0][aoffr];
      s16x8 av1 = *(const s16x8*)&hbuf[prev >> 2][1][aoffr];
      f32x4 g4[4];
      #pragma unroll
      for (int t = 0; t < 4; t++){
        f32x4 a = ae[t];                 // C-init carries e-part + bias
        a = mf(av0, bz[t][0], a);
        a = mf(av1, bz[t][1], a);
        g4[t] = a;
      }

      // ---- ONE fan stage: hi half pulls rows 2,3; 2 cells per lane ----
      float z0[4], z1[4];
      #pragma unroll
      for (int t = 0; t < 4; t++){
        float s2 = __shfl_xor(g4[t][2], 32);
        float s3 = __shfl_xor(g4[t][3], 32);
        z0[t] = hi ? s2 : g4[t][0];
        z1[t] = hi ? s3 : g4[t][1];
      }

      // ---- gates in-register, 2 cells/lane (rows hi*2+{0,1}, unit jown) ----
      float iv0 = sigm_f(z0[0]), fv0 = sigm_f(z0[1]);
      float gv0 = tanh_f(z0[2]), ov0 = sigm_f(z0[3]);
      float iv1 = sigm_f(z1[0]), fv1 = sigm_f(z1[1]);
      float gv1 = tanh_f(z1[2]), ov1 = sigm_f(z1[3]);
      float c0 = fv0 * creg[0] + iv0 * gv0;  creg[0] = c0;
      float c1 = fv1 * creg[1] + iv1 * gv1;  creg[1] = c1;
      u16 hb0 = f2bf(ov0 * tanh_f(c0));
      u16 hb1 = f2bf(ov1 * tanh_f(c1));
      if (wrt){
        const int m0 = sl*4 + hi*2;            // row = hi*2 + rp
        hbuf[m0 >> 4][jown >> 5][((m0 & 15) + eo16)*8 + (jown & 7)] = hb0;
        const int m1 = m0 + 1;
        hbuf[m1 >> 4][jown >> 5][((m1 & 15) + eo16)*8 + (jown & 7)] = hb1;
      }

      // ---- pre-barrier: next step's e-frags + e-part MFMAs (off-chain) ----
      if (sl < 15){
        e0 = *(const s16x8*)&ering[sl + 1][ln*8];
        e1 = *(const s16x8*)&ering[sl + 1][512 + ln*8];
        #pragma unroll
        for (int t = 0; t < 4; t++){
          f32x4 a = bgv[t];
          a = mf(e1, bz[t][3], a);
          a = mf(e0, bz[t][2], a);
          ae[t] = a;
        }
      }
      WGBAR();           // h visible -> next step may read (LDS only)
    }
  }

  dense_head(240);                       // last chunk's head
}

extern "C" void kernel_launch(void* const* d_in, const int* in_sizes, int n_in,
                              void* d_out, int out_size, void* d_ws, size_t ws_size,
                              hipStream_t stream) {
  (void)in_sizes; (void)n_in; (void)out_size; (void)d_ws; (void)ws_size;
  hipLaunchKernelGGL(LSTM_Seq2Dis_15272903704706_kernel,
                     dim3(512), dim3(TPB), 0, stream,
                     (const int*)d_in[0], d_in[1], d_in[2], d_in[3], d_in[4],
                     d_in[5], d_in[6], d_in[7], d_in[8], (float*)d_out);
}